// Round 1
// baseline (258.990 us; speedup 1.0000x reference)
//
#include <hip/hip_runtime.h>

#define HW 128      // H == W
#define CC 64       // C
#define C8V 8       // C/8
#define NB 16       // B

typedef _Float16 h1;
typedef _Float16 h2 __attribute__((ext_vector_type(2)));

__device__ __forceinline__ float dot2(uint a, uint b, float acc) {
#if __has_builtin(__builtin_amdgcn_fdot2)
  return __builtin_amdgcn_fdot2(__builtin_bit_cast(h2, a), __builtin_bit_cast(h2, b), acc, false);
#else
  h2 ha = __builtin_bit_cast(h2, a); h2 hb = __builtin_bit_cast(h2, b);
  return acc + (float)ha[0] * (float)hb[0] + (float)ha[1] * (float)hb[1];
#endif
}

__device__ __forceinline__ uint packh2(float a, float b) {
#if __has_builtin(__builtin_amdgcn_cvt_pkrtz)
  return __builtin_bit_cast(uint, __builtin_amdgcn_cvt_pkrtz(a, b));
#else
  h2 v; v[0] = (h1)a; v[1] = (h1)b; return __builtin_bit_cast(uint, v);
#endif
}

__device__ __forceinline__ ushort f2h(float a) { h1 v = (h1)a; return __builtin_bit_cast(ushort, v); }
__device__ __forceinline__ float  h2f(ushort a) { return (float)__builtin_bit_cast(h1, a); }

// ---------------------------------------------------------------------------
// K1: 1x1-conv projections q(8), k(8), v(64) from x(64), stored f16.
// Block = (b, row-pair), 256 threads = 2 rows x 128 w. Weights transposed
// into LDS ([c][o]) so the c-loop reads them as float4 broadcasts.
// ---------------------------------------------------------------------------
__global__ __launch_bounds__(256) void k_proj(
    const float* __restrict__ x,
    const float* __restrict__ Wq, const float* __restrict__ bq,
    const float* __restrict__ Wk, const float* __restrict__ bk,
    const float* __restrict__ Wv, const float* __restrict__ bv,
    ushort* __restrict__ q, ushort* __restrict__ k, ushort* __restrict__ v)
{
  __shared__ float wq_t[CC * C8V];   // [c][o]
  __shared__ float wk_t[CC * C8V];
  __shared__ float wv_t[CC * CC];    // [c][o]
  int t = threadIdx.x;
  for (int i = t; i < C8V * CC; i += 256) {
    int o = i >> 6, c = i & 63;
    wq_t[c * C8V + o] = Wq[i];
    wk_t[c * C8V + o] = Wk[i];
  }
  for (int i = t; i < CC * CC; i += 256) {
    int o = i >> 6, c = i & 63;
    wv_t[c * CC + o] = Wv[i];
  }
  __syncthreads();

  int b = blockIdx.x >> 6;
  int h = ((blockIdx.x & 63) << 1) | (t >> 7);
  int w = t & 127;
  size_t plane = (size_t)HW * HW;
  const float* xp = x + ((size_t)(b * CC) * HW + h) * HW + w;

  float qa[C8V], ka[C8V], va[CC];
  #pragma unroll
  for (int o = 0; o < C8V; ++o) { qa[o] = bq[o]; ka[o] = bk[o]; }
  #pragma unroll
  for (int o = 0; o < CC; ++o) va[o] = bv[o];

  for (int c = 0; c < CC; ++c) {
    float xc = xp[(size_t)c * plane];
    const float4* wq4 = (const float4*)&wq_t[c * C8V];
    const float4* wk4 = (const float4*)&wk_t[c * C8V];
    const float4* wv4 = (const float4*)&wv_t[c * CC];
    #pragma unroll
    for (int i = 0; i < 2; ++i) {
      float4 a = wq4[i], bb = wk4[i];
      qa[i*4+0] = fmaf(a.x, xc, qa[i*4+0]); qa[i*4+1] = fmaf(a.y, xc, qa[i*4+1]);
      qa[i*4+2] = fmaf(a.z, xc, qa[i*4+2]); qa[i*4+3] = fmaf(a.w, xc, qa[i*4+3]);
      ka[i*4+0] = fmaf(bb.x, xc, ka[i*4+0]); ka[i*4+1] = fmaf(bb.y, xc, ka[i*4+1]);
      ka[i*4+2] = fmaf(bb.z, xc, ka[i*4+2]); ka[i*4+3] = fmaf(bb.w, xc, ka[i*4+3]);
    }
    #pragma unroll
    for (int i = 0; i < 16; ++i) {
      float4 wv4v = wv4[i];
      va[i*4+0] = fmaf(wv4v.x, xc, va[i*4+0]); va[i*4+1] = fmaf(wv4v.y, xc, va[i*4+1]);
      va[i*4+2] = fmaf(wv4v.z, xc, va[i*4+2]); va[i*4+3] = fmaf(wv4v.w, xc, va[i*4+3]);
    }
  }

  ushort* qb = q + ((size_t)(b * C8V) * HW + h) * HW + w;
  ushort* kb = k + ((size_t)(b * C8V) * HW + h) * HW + w;
  ushort* vb = v + ((size_t)(b * CC)  * HW + h) * HW + w;
  #pragma unroll
  for (int o = 0; o < C8V; ++o) { qb[(size_t)o * plane] = f2h(qa[o]); kb[(size_t)o * plane] = f2h(ka[o]); }
  #pragma unroll
  for (int o = 0; o < CC; ++o) vb[(size_t)o * plane] = f2h(va[o]);
}

// ---------------------------------------------------------------------------
// K2: 128x128 f16 plane transpose (one plane per block), u32-packed I/O.
// ---------------------------------------------------------------------------
__global__ __launch_bounds__(256) void k_transpose(const ushort* __restrict__ in,
                                                   ushort* __restrict__ out)
{
  __shared__ ushort tl[128 * 130];
  int t = threadIdx.x;
  size_t base = (size_t)blockIdx.x * (HW * HW);
  const uint* ip = (const uint*)(in + base);
  uint* op = (uint*)(out + base);
  int c2 = t & 63;       // column pair (c = 2*c2)
  int r0 = t >> 6;       // 0..3
  for (int it = 0; it < 32; ++it) {
    int r = it * 4 + r0;
    uint val = ip[r * 64 + c2];
    *(uint*)&tl[r * 130 + c2 * 2] = val;
  }
  __syncthreads();
  for (int it = 0; it < 32; ++it) {
    int wcol = it * 4 + r0;
    int hh = c2 * 2;
    uint lo = tl[hh * 130 + wcol];
    uint hi = tl[(hh + 1) * 130 + wcol];
    op[wcol * 64 + c2] = lo | (hi << 16);
  }
}

// ---------------------------------------------------------------------------
// K3: generic row attention. Arrays are (B, Cdim, R, L=128) f16.
// Block = (b, r); thread t = position in row. MASK=true skips j==t (diag).
// Emits unnormalized O (f16, same layout as v) + per-pixel running (m, s).
// K row tile in LDS [j][c] (16B rows); V pair-interleaved [j/2][c] as u32
// so the O update is one v_dot2_f32_f16 per channel per j-pair.
// ---------------------------------------------------------------------------
template<bool MASK>
__global__ __launch_bounds__(128) void k_attn(
    const ushort* __restrict__ q, const ushort* __restrict__ kk, const ushort* __restrict__ v,
    ushort* __restrict__ o, float* __restrict__ m_out, float* __restrict__ s_out)
{
  __shared__ ushort k_l[HW * 8];    // [j][c]  rows of 16B
  __shared__ uint   v_l[64 * 68];   // [jp][c] (v[2jp][c] lo, v[2jp+1][c] hi), pad 4
  int t = threadIdx.x;
  int br = blockIdx.x;
  int b = br >> 7, r = br & 127;
  size_t plane = (size_t)HW * HW;

  uint qp[4];
  {
    const ushort* qb = q + ((size_t)(b * C8V) * HW + r) * HW + t;
    #pragma unroll
    for (int i = 0; i < 4; ++i) {
      uint lo = qb[(size_t)(2 * i) * plane];
      uint hi = qb[(size_t)(2 * i + 1) * plane];
      qp[i] = lo | (hi << 16);
    }
  }
  {
    const ushort* kb = kk + ((size_t)(b * C8V) * HW + r) * HW + t;
    #pragma unroll
    for (int c = 0; c < 8; ++c) k_l[t * 8 + c] = kb[(size_t)c * plane];
  }
  {
    const ushort* vb = v + ((size_t)(b * CC) * HW + r) * HW + t;
    ushort* vh = reinterpret_cast<ushort*>(v_l);
    int jp = t >> 1, lo = t & 1;
    #pragma unroll 8
    for (int c = 0; c < CC; ++c)
      vh[(jp * 68 + c) * 2 + lo] = vb[(size_t)c * plane];
  }
  __syncthreads();

  // sweep 1: online running max + sum (branchless; exp(-inf)=0)
  float m = -1e30f, s = 0.f;
  for (int j = 0; j < HW; ++j) {
    uint4 kr = *reinterpret_cast<const uint4*>(&k_l[j * 8]);
    float e = dot2(qp[0], kr.x, 0.f);
    e = dot2(qp[1], kr.y, e);
    e = dot2(qp[2], kr.z, e);
    e = dot2(qp[3], kr.w, e);
    if (MASK && j == t) e = -INFINITY;
    float mn = fmaxf(m, e);
    s = s * __expf(m - mn) + __expf(e - mn);
    m = mn;
  }

  // sweep 2: O accumulation with final m (identical e recompute => p <= 1)
  float oa[CC];
  #pragma unroll
  for (int c = 0; c < CC; ++c) oa[c] = 0.f;
  for (int jp = 0; jp < 64; ++jp) {
    uint4 kr0 = *reinterpret_cast<const uint4*>(&k_l[(2 * jp) * 8]);
    uint4 kr1 = *reinterpret_cast<const uint4*>(&k_l[(2 * jp + 1) * 8]);
    float e0 = dot2(qp[0], kr0.x, 0.f);
    e0 = dot2(qp[1], kr0.y, e0);
    e0 = dot2(qp[2], kr0.z, e0);
    e0 = dot2(qp[3], kr0.w, e0);
    float e1 = dot2(qp[0], kr1.x, 0.f);
    e1 = dot2(qp[1], kr1.y, e1);
    e1 = dot2(qp[2], kr1.z, e1);
    e1 = dot2(qp[3], kr1.w, e1);
    float p0 = (MASK && 2 * jp == t)     ? 0.f : __expf(e0 - m);
    float p1 = (MASK && 2 * jp + 1 == t) ? 0.f : __expf(e1 - m);
    uint pp = packh2(p0, p1);
    const uint* vr = &v_l[jp * 68];
    #pragma unroll
    for (int cq = 0; cq < 16; ++cq) {
      uint4 vv = *reinterpret_cast<const uint4*>(&vr[cq * 4]);
      oa[cq*4+0] = dot2(pp, vv.x, oa[cq*4+0]);
      oa[cq*4+1] = dot2(pp, vv.y, oa[cq*4+1]);
      oa[cq*4+2] = dot2(pp, vv.z, oa[cq*4+2]);
      oa[cq*4+3] = dot2(pp, vv.w, oa[cq*4+3]);
    }
  }

  {
    ushort* ob = o + ((size_t)(b * CC) * HW + r) * HW + t;
    #pragma unroll
    for (int c = 0; c < CC; ++c) ob[(size_t)c * plane] = f2h(oa[c]);
  }
  m_out[(size_t)br * HW + t] = m;
  s_out[(size_t)br * HW + t] = s;
}

// ---------------------------------------------------------------------------
// K4: merge the two softmax halves exactly and apply gamma + residual.
// Block = (b, 32x32 tile, c-group of 16). oHT read via LDS tile transpose.
// ---------------------------------------------------------------------------
__global__ __launch_bounds__(256) void k_merge(
    const ushort* __restrict__ oHT, const ushort* __restrict__ oW,
    const float* __restrict__ mH, const float* __restrict__ sH,
    const float* __restrict__ mW, const float* __restrict__ sW,
    const float* __restrict__ x, const float* __restrict__ gamma,
    float* __restrict__ out)
{
  __shared__ float mH_l[32 * 33], sH_l[32 * 33];
  __shared__ float aH_l[32 * 33], aW_l[32 * 33];
  __shared__ float tile_l[32 * 33];
  int t = threadIdx.x;
  int bid = blockIdx.x;
  int cg = bid & 3;
  int tile = (bid >> 2) & 15;
  int b = bid >> 6;
  int h0 = (tile >> 2) * 32, w0 = (tile & 3) * 32;
  float g = gamma[0];

  // A1: stats of the H (column) pass live transposed: load along h.
  for (int it = 0; it < 4; ++it) {
    int p = it * 256 + t;
    int wl = p >> 5, hl = p & 31;
    size_t idx = ((size_t)(b * HW) + (w0 + wl)) * HW + (h0 + hl);
    mH_l[wl * 33 + hl] = mH[idx];
    sH_l[wl * 33 + hl] = sH[idx];
  }
  __syncthreads();
  // A2: combine with W-pass stats -> per-pixel alpha_H, alpha_W.
  for (int it = 0; it < 4; ++it) {
    int p = it * 256 + t;
    int hl = p >> 5, wl = p & 31;
    size_t idx = ((size_t)(b * HW) + (h0 + hl)) * HW + (w0 + wl);
    float mw = mW[idx], sw = sW[idx];
    float mh = mH_l[wl * 33 + hl], sh = sH_l[wl * 33 + hl];
    float mm = fmaxf(mh, mw);
    float eh = __expf(mh - mm), ew = __expf(mw - mm);
    float inv = 1.f / (sh * eh + sw * ew);
    aH_l[wl * 33 + hl] = eh * inv;
    aW_l[hl * 33 + wl] = ew * inv;
  }
  __syncthreads();

  for (int ci = 0; ci < 16; ++ci) {
    int c = cg * 16 + ci;
    // B1: load oHT tile (coalesced along h), scale, park [w][h] in LDS.
    for (int it = 0; it < 4; ++it) {
      int p = it * 256 + t;
      int wl = p >> 5, hl = p & 31;
      size_t idx = ((size_t)((b * CC + c) * HW) + (w0 + wl)) * HW + (h0 + hl);
      tile_l[wl * 33 + hl] = h2f(oHT[idx]) * aH_l[wl * 33 + hl];
    }
    __syncthreads();
    // B2: natural orientation: combine, gamma, residual, store.
    for (int it = 0; it < 4; ++it) {
      int p = it * 256 + t;
      int hl = p >> 5, wl = p & 31;
      size_t idx = ((size_t)((b * CC + c) * HW) + (h0 + hl)) * HW + (w0 + wl);
      float ow = h2f(oW[idx]) * aW_l[hl * 33 + wl];
      out[idx] = g * (tile_l[wl * 33 + hl] + ow) + x[idx];
    }
    __syncthreads();
  }
}

extern "C" void kernel_launch(void* const* d_in, const int* in_sizes, int n_in,
                              void* d_out, int out_size, void* d_ws, size_t ws_size,
                              hipStream_t stream)
{
  const float* x     = (const float*)d_in[0];
  const float* Wq    = (const float*)d_in[1];
  const float* bq    = (const float*)d_in[2];
  const float* Wk    = (const float*)d_in[3];
  const float* bk    = (const float*)d_in[4];
  const float* Wv    = (const float*)d_in[5];
  const float* bv    = (const float*)d_in[6];
  const float* gamma = (const float*)d_in[7];
  float* out = (float*)d_out;

  char* w = (char*)d_ws;
  size_t np = (size_t)NB * HW * HW;   // 262144 pixels
  ushort* q   = (ushort*)w;  w += np * C8V * 2;
  ushort* k   = (ushort*)w;  w += np * C8V * 2;
  ushort* qT  = (ushort*)w;  w += np * C8V * 2;
  ushort* kT  = (ushort*)w;  w += np * C8V * 2;
  ushort* v   = (ushort*)w;  w += np * CC * 2;
  ushort* vT  = (ushort*)w;  w += np * CC * 2;
  ushort* oW  = (ushort*)w;  w += np * CC * 2;
  ushort* oHT = (ushort*)w;  w += np * CC * 2;
  float* mW = (float*)w;  w += np * 4;
  float* sW = (float*)w;  w += np * 4;
  float* mH = (float*)w;  w += np * 4;
  float* sH = (float*)w;  w += np * 4;
  if ((size_t)(w - (char*)d_ws) > ws_size) return;  // ws too small: bail (diagnosable)

  k_proj<<<NB * HW / 2, 256, 0, stream>>>(x, Wq, bq, Wk, bk, Wv, bv, q, k, v);
  k_transpose<<<NB * C8V, 256, 0, stream>>>(q, qT);
  k_transpose<<<NB * C8V, 256, 0, stream>>>(k, kT);
  k_transpose<<<NB * CC,  256, 0, stream>>>(v, vT);
  k_attn<false><<<NB * HW, 128, 0, stream>>>(q,  k,  v,  oW,  mW, sW);
  k_attn<true ><<<NB * HW, 128, 0, stream>>>(qT, kT, vT, oHT, mH, sH);
  k_merge<<<NB * 16 * 4, 256, 0, stream>>>(oHT, oW, mH, sH, mW, sW, x, gamma, out);
}

// Round 2
// 130.562 us; speedup vs baseline: 1.9837x; 1.9837x over previous
//
#include <hip/hip_runtime.h>

#define HW 128      // H == W
#define CC 64       // C
#define C8V 8       // C/8
#define NB 16       // B

typedef _Float16 h1;
typedef _Float16 h2 __attribute__((ext_vector_type(2)));
typedef _Float16 half8 __attribute__((ext_vector_type(8)));
typedef float float16v __attribute__((ext_vector_type(16)));
typedef uint uv4 __attribute__((ext_vector_type(4)));

__device__ __forceinline__ uint packh2(float a, float b) {
#if __has_builtin(__builtin_amdgcn_cvt_pkrtz)
  return __builtin_bit_cast(uint, __builtin_amdgcn_cvt_pkrtz(a, b));
#else
  h2 v; v[0] = (h1)a; v[1] = (h1)b; return __builtin_bit_cast(uint, v);
#endif
}
__device__ __forceinline__ ushort f2h(float a) { h1 v = (h1)a; return __builtin_bit_cast(ushort, v); }
__device__ __forceinline__ float  h2f(ushort a) { return (float)__builtin_bit_cast(h1, a); }

__device__ __forceinline__ float16v mfma16(uv4 a, uv4 b, float16v c) {
  return __builtin_amdgcn_mfma_f32_32x32x16_f16(
      __builtin_bit_cast(half8, a), __builtin_bit_cast(half8, b), c, 0, 0, 0);
}

// ---------------------------------------------------------------------------
// K1: projection GEMM via MFMA. One block per (b, h) row, 4 waves.
// out[o, w] = sum_c W80[o, c] * x[c, w] + bias[o], o in [0,80) = q(8)|k(8)|v(64).
// A = W (M=96 padded, K=64), B = x^T staged f16 in LDS (rows padded to 72).
// ---------------------------------------------------------------------------
__global__ __launch_bounds__(256) void k_proj(
    const float* __restrict__ x,
    const float* __restrict__ Wq, const float* __restrict__ bq,
    const float* __restrict__ Wk, const float* __restrict__ bk,
    const float* __restrict__ Wv, const float* __restrict__ bv,
    ushort* __restrict__ q, ushort* __restrict__ k, ushort* __restrict__ v)
{
  alignas(16) __shared__ ushort smem[16128];   // x_l[128][72] | W_l[96][72]; o_l[80][128] aliases
  __shared__ float bias_l[96];
  ushort* x_l = smem;                 // [w][c], row stride 72
  ushort* W_l = smem + 128 * 72;      // [o][c], row stride 72

  int t = threadIdx.x;
  int lane = t & 63, wv = t >> 6;
  int b = blockIdx.x >> 7, r = blockIdx.x & 127;

  // stage weights (f16) [o][c]
  #pragma unroll
  for (int i = 0; i < 20; ++i) {
    int idx = t + 256 * i; int o_ = idx >> 6, c = idx & 63;
    float wval = (o_ < 8) ? Wq[o_ * 64 + c] : (o_ < 16) ? Wk[(o_ - 8) * 64 + c] : Wv[(o_ - 16) * 64 + c];
    W_l[o_ * 72 + c] = f2h(wval);
  }
  if (t < 96) bias_l[t] = (t < 8) ? bq[t] : (t < 16) ? bk[t - 8] : (t < 80) ? bv[t - 16] : 0.f;

  // stage x row transposed -> x_l[w][c] (f16), coalesced float4 reads
  const float* xrow = x + (size_t)(b * CC) * (HW * HW) + (size_t)r * HW;
  #pragma unroll
  for (int i = 0; i < 8; ++i) {
    int idx = t + 256 * i; int c = idx >> 5, w4 = idx & 31;
    float4 xv = *(const float4*)(xrow + (size_t)c * (HW * HW) + w4 * 4);
    x_l[(w4 * 4 + 0) * 72 + c] = f2h(xv.x);
    x_l[(w4 * 4 + 1) * 72 + c] = f2h(xv.y);
    x_l[(w4 * 4 + 2) * 72 + c] = f2h(xv.z);
    x_l[(w4 * 4 + 3) * 72 + c] = f2h(xv.w);
  }
  __syncthreads();

  int w = 32 * wv + (lane & 31);
  float16v acc0 = {}, acc1 = {}, acc2 = {};
  #pragma unroll
  for (int ks = 0; ks < 4; ++ks) {
    int c0 = 8 * (lane >> 5) + 16 * ks;
    uv4 Bx = *(const uv4*)&x_l[w * 72 + c0];
    uv4 a0 = *(const uv4*)&W_l[((lane & 31) + 0) * 72 + c0];
    uv4 a1 = *(const uv4*)&W_l[((lane & 31) + 32) * 72 + c0];
    uv4 a2 = *(const uv4*)&W_l[((lane & 31) + 64) * 72 + c0];
    acc0 = mfma16(a0, Bx, acc0);
    acc1 = mfma16(a1, Bx, acc1);
    acc2 = mfma16(a2, Bx, acc2);
  }
  __syncthreads();   // x_l/W_l dead

  // epilogue: bias + f16, repack via LDS [o][w]
  ushort* o_l = smem;
  int hi = lane >> 5;
  #pragma unroll
  for (int reg = 0; reg < 16; ++reg) {
    int orow = (reg & 3) + 8 * (reg >> 2) + 4 * hi;
    o_l[(orow +  0) * 128 + w] = f2h(acc0[reg] + bias_l[orow]);
    o_l[(orow + 32) * 128 + w] = f2h(acc1[reg] + bias_l[orow + 32]);
    if (orow + 64 < 80)
      o_l[(orow + 64) * 128 + w] = f2h(acc2[reg] + bias_l[orow + 64]);
  }
  __syncthreads();

  ushort* qb = q + (size_t)(b * C8V) * (HW * HW) + (size_t)r * HW;
  ushort* kb = k + (size_t)(b * C8V) * (HW * HW) + (size_t)r * HW;
  ushort* vb = v + (size_t)(b * CC)  * (HW * HW) + (size_t)r * HW;
  #pragma unroll
  for (int i = 0; i < 5; ++i) {
    int idx = t + 256 * i; int o_ = idx >> 4, w8 = idx & 15;
    uv4 val = *(const uv4*)&o_l[o_ * 128 + w8 * 8];
    ushort* dst = (o_ < 8) ? qb + (size_t)o_ * (HW * HW)
                : (o_ < 16) ? kb + (size_t)(o_ - 8) * (HW * HW)
                            : vb + (size_t)(o_ - 16) * (HW * HW);
    *(uv4*)(dst + w8 * 8) = val;
  }
}

// ---------------------------------------------------------------------------
// K2: 128x128 f16 plane transpose (one plane per block), u32-packed I/O.
// ---------------------------------------------------------------------------
__global__ __launch_bounds__(256) void k_transpose(const ushort* __restrict__ in,
                                                   ushort* __restrict__ out)
{
  __shared__ ushort tl[128 * 130];
  int t = threadIdx.x;
  size_t base = (size_t)blockIdx.x * (HW * HW);
  const uint* ip = (const uint*)(in + base);
  uint* op = (uint*)(out + base);
  int c2 = t & 63;
  int r0 = t >> 6;
  for (int it = 0; it < 32; ++it) {
    int r = it * 4 + r0;
    uint val = ip[r * 64 + c2];
    *(uint*)&tl[r * 130 + c2 * 2] = val;
  }
  __syncthreads();
  for (int it = 0; it < 32; ++it) {
    int wcol = it * 4 + r0;
    int hh = c2 * 2;
    uint lo = tl[hh * 130 + wcol];
    uint hi = tl[(hh + 1) * 130 + wcol];
    op[wcol * 64 + c2] = lo | (hi << 16);
  }
}

// ---------------------------------------------------------------------------
// K3: MFMA row attention. Arrays (B, Cdim, R, L=128) f16. Block=(b,r), 4 waves.
// Swapped QK^T: E = mfma(K, Q) -> lane holds E[key, query=lane&31+32*wv] in 64
// f32 regs. Softmax register-local + one shfl_xor(32). P packed to f16 feeds
// PV's B operand directly (D-layout key == B-layout k per 16-key step, with 4
// shfl_xor(32) fixing the half swap). V in LDS, XOR-swizzled (c&15)<<4.
// Emits unnormalized O (f16) + per-pixel (m, s).
// ---------------------------------------------------------------------------
template<bool MASK>
__global__ __launch_bounds__(256) void k_attn(
    const ushort* __restrict__ q, const ushort* __restrict__ kk, const ushort* __restrict__ v,
    ushort* __restrict__ o, float* __restrict__ m_out, float* __restrict__ s_out)
{
  alignas(16) __shared__ ushort Q_l[128][16];   // [w][c], c 8..15 zero
  alignas(16) __shared__ ushort K_l[128][16];   // [j][c], c 8..15 zero
  alignas(16) __shared__ uint   V_l[64 * 64];   // [c][j] swizzled: byte = c*256 + (off ^ ((c&15)<<4))

  int t = threadIdx.x;
  int lane = t & 63, wv = t >> 6;
  int hi = lane >> 5;
  int b = blockIdx.x >> 7, r = blockIdx.x & 127;
  size_t plane32 = (size_t)(HW * HW) / 2;

  if (t < 128) {
    *(uv4*)&Q_l[t][8] = (uv4){0, 0, 0, 0};
    *(uv4*)&K_l[t][8] = (uv4){0, 0, 0, 0};
  }
  const uint* qrow = (const uint*)q + (size_t)(b * C8V) * plane32 + (size_t)r * 64;
  const uint* krow = (const uint*)kk + (size_t)(b * C8V) * plane32 + (size_t)r * 64;
  #pragma unroll
  for (int i = 0; i < 2; ++i) {
    int idx = t + 256 * i; int c = idx >> 6, w2 = idx & 63;
    uint qv = qrow[(size_t)c * plane32 + w2];
    Q_l[2 * w2][c] = (ushort)(qv & 0xffff); Q_l[2 * w2 + 1][c] = (ushort)(qv >> 16);
    uint kv = krow[(size_t)c * plane32 + w2];
    K_l[2 * w2][c] = (ushort)(kv & 0xffff); K_l[2 * w2 + 1][c] = (ushort)(kv >> 16);
  }
  const uint* vrow = (const uint*)v + (size_t)(b * CC) * plane32 + (size_t)r * 64;
  #pragma unroll
  for (int i = 0; i < 16; ++i) {
    int idx = t + 256 * i; int c = idx >> 6, j2 = idx & 63;
    uint val = vrow[(size_t)c * plane32 + j2];
    uint byteoff = c * 256 + ((4 * j2) ^ ((c & 15) << 4));
    V_l[byteoff >> 2] = val;
  }
  __syncthreads();

  // QK^T: E[key, query]
  uv4 Bq = *(const uv4*)&Q_l[(lane & 31) + 32 * wv][hi * 8];
  float16v e[4];
  #pragma unroll
  for (int mt = 0; mt < 4; ++mt) {
    uv4 ka = *(const uv4*)&K_l[(lane & 31) + 32 * mt][hi * 8];
    float16v z = {};
    e[mt] = mfma16(ka, Bq, z);
  }

  // softmax (register-local per query = lane&31 + 32*wv; halves duplicate)
  int qg = 32 * wv + (lane & 31);
  float m = -INFINITY;
  #pragma unroll
  for (int mt = 0; mt < 4; ++mt) {
    #pragma unroll
    for (int reg = 0; reg < 16; ++reg) {
      float ev = e[mt][reg];
      if (MASK) {
        int key = 32 * mt + ((reg & 3) + 8 * (reg >> 2) + 4 * hi);
        ev = (key == qg) ? -INFINITY : ev;
        e[mt][reg] = ev;
      }
      m = fmaxf(m, ev);
    }
  }
  m = fmaxf(m, __shfl_xor(m, 32));
  float s = 0.f;
  #pragma unroll
  for (int mt = 0; mt < 4; ++mt) {
    #pragma unroll
    for (int reg = 0; reg < 16; ++reg) {
      float p = __expf(e[mt][reg] - m);
      e[mt][reg] = p;
      s += p;
    }
  }
  s += __shfl_xor(s, 32);
  if (lane < 32) {
    m_out[(size_t)blockIdx.x * HW + qg] = m;
    s_out[(size_t)blockIdx.x * HW + qg] = s;
  }

  // PV: O[c, w] = sum_j V[c, j] P[j, w]
  float16v acc0 = {}, acc1 = {};
  #pragma unroll
  for (int s8 = 0; s8 < 8; ++s8) {
    int mt = s8 >> 1, hf = s8 & 1;
    float p0 = e[mt][8 * hf + 0], p1 = e[mt][8 * hf + 1];
    float p2 = e[mt][8 * hf + 2], p3 = e[mt][8 * hf + 3];
    float p4 = e[mt][8 * hf + 4], p5 = e[mt][8 * hf + 5];
    float p6 = e[mt][8 * hf + 6], p7 = e[mt][8 * hf + 7];
    uint X = packh2(p0, p1), Y = packh2(p2, p3), Z = packh2(p4, p5), Wp = packh2(p6, p7);
    uint Xs = __shfl_xor(X, 32), Ys = __shfl_xor(Y, 32);
    uint Zs = __shfl_xor(Z, 32), Ws = __shfl_xor(Wp, 32);
    uv4 Bp;
    Bp[0] = (hi == 0) ? X  : Zs;   // k 0,1  | k 8,9
    Bp[1] = (hi == 0) ? Y  : Ws;   // k 2,3  | k 10,11
    Bp[2] = (hi == 0) ? Xs : Z;    // k 4,5  | k 12,13
    Bp[3] = (hi == 0) ? Ys : Wp;   // k 6,7  | k 14,15
    #pragma unroll
    for (int ct = 0; ct < 2; ++ct) {
      int c = (lane & 31) + 32 * ct;
      uint byteoff = c * 256 + ((16 * (hi + 2 * s8)) ^ ((c & 15) << 4));
      uv4 va = *(const uv4*)((const char*)V_l + byteoff);
      if (ct == 0) acc0 = mfma16(va, Bp, acc0);
      else         acc1 = mfma16(va, Bp, acc1);
    }
  }

  // epilogue: repack O via LDS (aliases V_l), coalesced uint4 stores
  __syncthreads();
  ushort* o_l = (ushort*)V_l;   // [c][w]
  int w = 32 * wv + (lane & 31);
  #pragma unroll
  for (int reg = 0; reg < 16; ++reg) {
    int c = (reg & 3) + 8 * (reg >> 2) + 4 * hi;
    o_l[(c +  0) * 128 + w] = f2h(acc0[reg]);
    o_l[(c + 32) * 128 + w] = f2h(acc1[reg]);
  }
  __syncthreads();
  ushort* ob = o + (size_t)(b * CC) * (HW * HW) + (size_t)r * HW;
  #pragma unroll
  for (int i = 0; i < 4; ++i) {
    int idx = t + 256 * i; int c = idx >> 4, w8 = idx & 15;
    *(uv4*)(ob + (size_t)c * (HW * HW) + w8 * 8) = *(const uv4*)&o_l[c * 128 + w8 * 8];
  }
}

// ---------------------------------------------------------------------------
// K4: merge the two softmax halves exactly and apply gamma + residual.
// ---------------------------------------------------------------------------
__global__ __launch_bounds__(256) void k_merge(
    const ushort* __restrict__ oHT, const ushort* __restrict__ oW,
    const float* __restrict__ mH, const float* __restrict__ sH,
    const float* __restrict__ mW, const float* __restrict__ sW,
    const float* __restrict__ x, const float* __restrict__ gamma,
    float* __restrict__ out)
{
  __shared__ float mH_l[32 * 33], sH_l[32 * 33];
  __shared__ float aH_l[32 * 33], aW_l[32 * 33];
  __shared__ float tile_l[32 * 33];
  int t = threadIdx.x;
  int bid = blockIdx.x;
  int cg = bid & 3;
  int tile = (bid >> 2) & 15;
  int b = bid >> 6;
  int h0 = (tile >> 2) * 32, w0 = (tile & 3) * 32;
  float g = gamma[0];

  for (int it = 0; it < 4; ++it) {
    int p = it * 256 + t;
    int wl = p >> 5, hl = p & 31;
    size_t idx = ((size_t)(b * HW) + (w0 + wl)) * HW + (h0 + hl);
    mH_l[wl * 33 + hl] = mH[idx];
    sH_l[wl * 33 + hl] = sH[idx];
  }
  __syncthreads();
  for (int it = 0; it < 4; ++it) {
    int p = it * 256 + t;
    int hl = p >> 5, wl = p & 31;
    size_t idx = ((size_t)(b * HW) + (h0 + hl)) * HW + (w0 + wl);
    float mw = mW[idx], sw = sW[idx];
    float mh = mH_l[wl * 33 + hl], sh = sH_l[wl * 33 + hl];
    float mm = fmaxf(mh, mw);
    float eh = __expf(mh - mm), ew = __expf(mw - mm);
    float inv = 1.f / (sh * eh + sw * ew);
    aH_l[wl * 33 + hl] = eh * inv;
    aW_l[hl * 33 + wl] = ew * inv;
  }
  __syncthreads();

  for (int ci = 0; ci < 16; ++ci) {
    int c = cg * 16 + ci;
    for (int it = 0; it < 4; ++it) {
      int p = it * 256 + t;
      int wl = p >> 5, hl = p & 31;
      size_t idx = ((size_t)((b * CC + c) * HW) + (w0 + wl)) * HW + (h0 + hl);
      tile_l[wl * 33 + hl] = h2f(oHT[idx]) * aH_l[wl * 33 + hl];
    }
    __syncthreads();
    for (int it = 0; it < 4; ++it) {
      int p = it * 256 + t;
      int hl = p >> 5, wl = p & 31;
      size_t idx = ((size_t)((b * CC + c) * HW) + (h0 + hl)) * HW + (w0 + wl);
      float ow = h2f(oW[idx]) * aW_l[hl * 33 + wl];
      out[idx] = g * (tile_l[wl * 33 + hl] + ow) + x[idx];
    }
    __syncthreads();
  }
}

extern "C" void kernel_launch(void* const* d_in, const int* in_sizes, int n_in,
                              void* d_out, int out_size, void* d_ws, size_t ws_size,
                              hipStream_t stream)
{
  const float* x     = (const float*)d_in[0];
  const float* Wq    = (const float*)d_in[1];
  const float* bq    = (const float*)d_in[2];
  const float* Wk    = (const float*)d_in[3];
  const float* bk    = (const float*)d_in[4];
  const float* Wv    = (const float*)d_in[5];
  const float* bv    = (const float*)d_in[6];
  const float* gamma = (const float*)d_in[7];
  float* out = (float*)d_out;

  char* w = (char*)d_ws;
  size_t np = (size_t)NB * HW * HW;
  ushort* q   = (ushort*)w;  w += np * C8V * 2;
  ushort* k   = (ushort*)w;  w += np * C8V * 2;
  ushort* qT  = (ushort*)w;  w += np * C8V * 2;
  ushort* kT  = (ushort*)w;  w += np * C8V * 2;
  ushort* v   = (ushort*)w;  w += np * CC * 2;
  ushort* vT  = (ushort*)w;  w += np * CC * 2;
  ushort* oW  = (ushort*)w;  w += np * CC * 2;
  ushort* oHT = (ushort*)w;  w += np * CC * 2;
  float* mW = (float*)w;  w += np * 4;
  float* sW = (float*)w;  w += np * 4;
  float* mH = (float*)w;  w += np * 4;
  float* sH = (float*)w;  w += np * 4;
  if ((size_t)(w - (char*)d_ws) > ws_size) return;

  k_proj<<<NB * HW, 256, 0, stream>>>(x, Wq, bq, Wk, bk, Wv, bv, q, k, v);
  k_transpose<<<NB * C8V, 256, 0, stream>>>(q, qT);
  k_transpose<<<NB * C8V, 256, 0, stream>>>(k, kT);
  k_transpose<<<NB * CC,  256, 0, stream>>>(v, vT);
  k_attn<false><<<NB * HW, 256, 0, stream>>>(q,  k,  v,  oW,  mW, sW);
  k_attn<true ><<<NB * HW, 256, 0, stream>>>(qT, kT, vT, oHT, mH, sH);
  k_merge<<<NB * 16 * 4, 256, 0, stream>>>(oHT, oW, mH, sH, mW, sW, x, gamma, out);
}

// Round 3
// 128.503 us; speedup vs baseline: 2.0154x; 1.0160x over previous
//
#include <hip/hip_runtime.h>

#define HW 128      // H == W
#define CC 64       // C
#define C8V 8       // C/8
#define NB 16       // B

typedef _Float16 h1;
typedef _Float16 h2 __attribute__((ext_vector_type(2)));
typedef _Float16 half8 __attribute__((ext_vector_type(8)));
typedef float float16v __attribute__((ext_vector_type(16)));
typedef uint uv4 __attribute__((ext_vector_type(4)));

__device__ __forceinline__ uint packh2(float a, float b) {
#if __has_builtin(__builtin_amdgcn_cvt_pkrtz)
  return __builtin_bit_cast(uint, __builtin_amdgcn_cvt_pkrtz(a, b));
#else
  h2 v; v[0] = (h1)a; v[1] = (h1)b; return __builtin_bit_cast(uint, v);
#endif
}
__device__ __forceinline__ ushort f2h(float a) { h1 v = (h1)a; return __builtin_bit_cast(ushort, v); }
__device__ __forceinline__ float  h2f(ushort a) { return (float)__builtin_bit_cast(h1, a); }

__device__ __forceinline__ float16v mfma16(uv4 a, uv4 b, float16v c) {
  return __builtin_amdgcn_mfma_f32_32x32x16_f16(
      __builtin_bit_cast(half8, a), __builtin_bit_cast(half8, b), c, 0, 0, 0);
}

// ---------------------------------------------------------------------------
// K1: projection GEMM via MFMA. One block per (b, h) row, 4 waves.
// ---------------------------------------------------------------------------
__global__ __launch_bounds__(256) void k_proj(
    const float* __restrict__ x,
    const float* __restrict__ Wq, const float* __restrict__ bq,
    const float* __restrict__ Wk, const float* __restrict__ bk,
    const float* __restrict__ Wv, const float* __restrict__ bv,
    ushort* __restrict__ q, ushort* __restrict__ k, ushort* __restrict__ v)
{
  alignas(16) __shared__ ushort smem[16128];   // x_l[128][72] | W_l[96][72]; o_l[80][128] aliases
  __shared__ float bias_l[96];
  ushort* x_l = smem;                 // [w][c], row stride 72
  ushort* W_l = smem + 128 * 72;      // [o][c], row stride 72

  int t = threadIdx.x;
  int lane = t & 63, wv = t >> 6;
  int b = blockIdx.x >> 7, r = blockIdx.x & 127;

  #pragma unroll
  for (int i = 0; i < 20; ++i) {
    int idx = t + 256 * i; int o_ = idx >> 6, c = idx & 63;
    float wval = (o_ < 8) ? Wq[o_ * 64 + c] : (o_ < 16) ? Wk[(o_ - 8) * 64 + c] : Wv[(o_ - 16) * 64 + c];
    W_l[o_ * 72 + c] = f2h(wval);
  }
  if (t < 96) bias_l[t] = (t < 8) ? bq[t] : (t < 16) ? bk[t - 8] : (t < 80) ? bv[t - 16] : 0.f;

  const float* xrow = x + (size_t)(b * CC) * (HW * HW) + (size_t)r * HW;
  #pragma unroll
  for (int i = 0; i < 8; ++i) {
    int idx = t + 256 * i; int c = idx >> 5, w4 = idx & 31;
    float4 xv = *(const float4*)(xrow + (size_t)c * (HW * HW) + w4 * 4);
    x_l[(w4 * 4 + 0) * 72 + c] = f2h(xv.x);
    x_l[(w4 * 4 + 1) * 72 + c] = f2h(xv.y);
    x_l[(w4 * 4 + 2) * 72 + c] = f2h(xv.z);
    x_l[(w4 * 4 + 3) * 72 + c] = f2h(xv.w);
  }
  __syncthreads();

  int w = 32 * wv + (lane & 31);
  float16v acc0 = {}, acc1 = {}, acc2 = {};
  #pragma unroll
  for (int ks = 0; ks < 4; ++ks) {
    int c0 = 8 * (lane >> 5) + 16 * ks;
    uv4 Bx = *(const uv4*)&x_l[w * 72 + c0];
    uv4 a0 = *(const uv4*)&W_l[((lane & 31) + 0) * 72 + c0];
    uv4 a1 = *(const uv4*)&W_l[((lane & 31) + 32) * 72 + c0];
    uv4 a2 = *(const uv4*)&W_l[((lane & 31) + 64) * 72 + c0];
    acc0 = mfma16(a0, Bx, acc0);
    acc1 = mfma16(a1, Bx, acc1);
    acc2 = mfma16(a2, Bx, acc2);
  }
  __syncthreads();

  ushort* o_l = smem;
  int hi = lane >> 5;
  #pragma unroll
  for (int reg = 0; reg < 16; ++reg) {
    int orow = (reg & 3) + 8 * (reg >> 2) + 4 * hi;
    o_l[(orow +  0) * 128 + w] = f2h(acc0[reg] + bias_l[orow]);
    o_l[(orow + 32) * 128 + w] = f2h(acc1[reg] + bias_l[orow + 32]);
    if (orow + 64 < 80)
      o_l[(orow + 64) * 128 + w] = f2h(acc2[reg] + bias_l[orow + 64]);
  }
  __syncthreads();

  ushort* qb = q + (size_t)(b * C8V) * (HW * HW) + (size_t)r * HW;
  ushort* kb = k + (size_t)(b * C8V) * (HW * HW) + (size_t)r * HW;
  ushort* vb = v + (size_t)(b * CC)  * (HW * HW) + (size_t)r * HW;
  #pragma unroll
  for (int i = 0; i < 5; ++i) {
    int idx = t + 256 * i; int o_ = idx >> 4, w8 = idx & 15;
    uv4 val = *(const uv4*)&o_l[o_ * 128 + w8 * 8];
    ushort* dst = (o_ < 8) ? qb + (size_t)o_ * (HW * HW)
                : (o_ < 16) ? kb + (size_t)(o_ - 8) * (HW * HW)
                            : vb + (size_t)(o_ - 16) * (HW * HW);
    *(uv4*)(dst + w8 * 8) = val;
  }
}

// ---------------------------------------------------------------------------
// K2: all three plane transposes in ONE launch (q->qT, k->kT, v->vT).
// ---------------------------------------------------------------------------
__global__ __launch_bounds__(256) void k_transpose_all(
    const ushort* __restrict__ q, ushort* __restrict__ qT,
    const ushort* __restrict__ k, ushort* __restrict__ kT,
    const ushort* __restrict__ v, ushort* __restrict__ vT)
{
  __shared__ ushort tl[128 * 130];
  int t = threadIdx.x;
  int p = blockIdx.x;
  const ushort* in; ushort* out;
  if (p < 128)      { size_t base = (size_t)p * (HW * HW);         in = q + base; out = qT + base; }
  else if (p < 256) { size_t base = (size_t)(p - 128) * (HW * HW); in = k + base; out = kT + base; }
  else              { size_t base = (size_t)(p - 256) * (HW * HW); in = v + base; out = vT + base; }
  const uint* ip = (const uint*)in;
  uint* op = (uint*)out;
  int c2 = t & 63;
  int r0 = t >> 6;
  for (int it = 0; it < 32; ++it) {
    int r = it * 4 + r0;
    uint val = ip[r * 64 + c2];
    *(uint*)&tl[r * 130 + c2 * 2] = val;
  }
  __syncthreads();
  for (int it = 0; it < 32; ++it) {
    int wcol = it * 4 + r0;
    int hh = c2 * 2;
    uint lo = tl[hh * 130 + wcol];
    uint hi = tl[(hh + 1) * 130 + wcol];
    op[wcol * 64 + c2] = lo | (hi << 16);
  }
}

// ---------------------------------------------------------------------------
// K3: MFMA row attention (unchanged).
// ---------------------------------------------------------------------------
template<bool MASK>
__global__ __launch_bounds__(256) void k_attn(
    const ushort* __restrict__ q, const ushort* __restrict__ kk, const ushort* __restrict__ v,
    ushort* __restrict__ o, float* __restrict__ m_out, float* __restrict__ s_out)
{
  alignas(16) __shared__ ushort Q_l[128][16];
  alignas(16) __shared__ ushort K_l[128][16];
  alignas(16) __shared__ uint   V_l[64 * 64];

  int t = threadIdx.x;
  int lane = t & 63, wv = t >> 6;
  int hi = lane >> 5;
  int b = blockIdx.x >> 7, r = blockIdx.x & 127;
  size_t plane32 = (size_t)(HW * HW) / 2;

  if (t < 128) {
    *(uv4*)&Q_l[t][8] = (uv4){0, 0, 0, 0};
    *(uv4*)&K_l[t][8] = (uv4){0, 0, 0, 0};
  }
  const uint* qrow = (const uint*)q + (size_t)(b * C8V) * plane32 + (size_t)r * 64;
  const uint* krow = (const uint*)kk + (size_t)(b * C8V) * plane32 + (size_t)r * 64;
  #pragma unroll
  for (int i = 0; i < 2; ++i) {
    int idx = t + 256 * i; int c = idx >> 6, w2 = idx & 63;
    uint qv = qrow[(size_t)c * plane32 + w2];
    Q_l[2 * w2][c] = (ushort)(qv & 0xffff); Q_l[2 * w2 + 1][c] = (ushort)(qv >> 16);
    uint kv = krow[(size_t)c * plane32 + w2];
    K_l[2 * w2][c] = (ushort)(kv & 0xffff); K_l[2 * w2 + 1][c] = (ushort)(kv >> 16);
  }
  const uint* vrow = (const uint*)v + (size_t)(b * CC) * plane32 + (size_t)r * 64;
  #pragma unroll
  for (int i = 0; i < 16; ++i) {
    int idx = t + 256 * i; int c = idx >> 6, j2 = idx & 63;
    uint val = vrow[(size_t)c * plane32 + j2];
    uint byteoff = c * 256 + ((4 * j2) ^ ((c & 15) << 4));
    V_l[byteoff >> 2] = val;
  }
  __syncthreads();

  uv4 Bq = *(const uv4*)&Q_l[(lane & 31) + 32 * wv][hi * 8];
  float16v e[4];
  #pragma unroll
  for (int mt = 0; mt < 4; ++mt) {
    uv4 ka = *(const uv4*)&K_l[(lane & 31) + 32 * mt][hi * 8];
    float16v z = {};
    e[mt] = mfma16(ka, Bq, z);
  }

  int qg = 32 * wv + (lane & 31);
  float m = -INFINITY;
  #pragma unroll
  for (int mt = 0; mt < 4; ++mt) {
    #pragma unroll
    for (int reg = 0; reg < 16; ++reg) {
      float ev = e[mt][reg];
      if (MASK) {
        int key = 32 * mt + ((reg & 3) + 8 * (reg >> 2) + 4 * hi);
        ev = (key == qg) ? -INFINITY : ev;
        e[mt][reg] = ev;
      }
      m = fmaxf(m, ev);
    }
  }
  m = fmaxf(m, __shfl_xor(m, 32));
  float s = 0.f;
  #pragma unroll
  for (int mt = 0; mt < 4; ++mt) {
    #pragma unroll
    for (int reg = 0; reg < 16; ++reg) {
      float p = __expf(e[mt][reg] - m);
      e[mt][reg] = p;
      s += p;
    }
  }
  s += __shfl_xor(s, 32);
  if (lane < 32) {
    m_out[(size_t)blockIdx.x * HW + qg] = m;
    s_out[(size_t)blockIdx.x * HW + qg] = s;
  }

  float16v acc0 = {}, acc1 = {};
  #pragma unroll
  for (int s8 = 0; s8 < 8; ++s8) {
    int mt = s8 >> 1, hf = s8 & 1;
    float p0 = e[mt][8 * hf + 0], p1 = e[mt][8 * hf + 1];
    float p2 = e[mt][8 * hf + 2], p3 = e[mt][8 * hf + 3];
    float p4 = e[mt][8 * hf + 4], p5 = e[mt][8 * hf + 5];
    float p6 = e[mt][8 * hf + 6], p7 = e[mt][8 * hf + 7];
    uint X = packh2(p0, p1), Y = packh2(p2, p3), Z = packh2(p4, p5), Wp = packh2(p6, p7);
    uint Xs = __shfl_xor(X, 32), Ys = __shfl_xor(Y, 32);
    uint Zs = __shfl_xor(Z, 32), Ws = __shfl_xor(Wp, 32);
    uv4 Bp;
    Bp[0] = (hi == 0) ? X  : Zs;
    Bp[1] = (hi == 0) ? Y  : Ws;
    Bp[2] = (hi == 0) ? Xs : Z;
    Bp[3] = (hi == 0) ? Ys : Wp;
    #pragma unroll
    for (int ct = 0; ct < 2; ++ct) {
      int c = (lane & 31) + 32 * ct;
      uint byteoff = c * 256 + ((16 * (hi + 2 * s8)) ^ ((c & 15) << 4));
      uv4 va = *(const uv4*)((const char*)V_l + byteoff);
      if (ct == 0) acc0 = mfma16(va, Bp, acc0);
      else         acc1 = mfma16(va, Bp, acc1);
    }
  }

  __syncthreads();
  ushort* o_l = (ushort*)V_l;
  int w = 32 * wv + (lane & 31);
  #pragma unroll
  for (int reg = 0; reg < 16; ++reg) {
    int c = (reg & 3) + 8 * (reg >> 2) + 4 * hi;
    o_l[(c +  0) * 128 + w] = f2h(acc0[reg]);
    o_l[(c + 32) * 128 + w] = f2h(acc1[reg]);
  }
  __syncthreads();
  ushort* ob = o + (size_t)(b * CC) * (HW * HW) + (size_t)r * HW;
  #pragma unroll
  for (int i = 0; i < 4; ++i) {
    int idx = t + 256 * i; int c = idx >> 4, w8 = idx & 15;
    *(uv4*)(ob + (size_t)c * (HW * HW) + w8 * 8) = *(const uv4*)&o_l[c * 128 + w8 * 8];
  }
}

// ---------------------------------------------------------------------------
// K4: merge, vectorized. Block = (b, 8-channel group, 32-w stripe, full h).
// Grid 16*8*4 = 512. oHT read coalesced uint4 along h; x/out float4; oW uint2.
// alphas computed once per block into LDS.
// ---------------------------------------------------------------------------
__global__ __launch_bounds__(256) void k_merge(
    const ushort* __restrict__ oHT, const ushort* __restrict__ oW,
    const float* __restrict__ mH, const float* __restrict__ sH,
    const float* __restrict__ mW, const float* __restrict__ sW,
    const float* __restrict__ x, const float* __restrict__ gamma,
    float* __restrict__ out)
{
  __shared__ float aH_l[32 * 132];   // [w][h] stride 132
  __shared__ float aW_l[128 * 33];   // [h][w] stride 33
  __shared__ float tile[32 * 132];   // [w][h] stride 132

  int t = threadIdx.x;
  int bid = blockIdx.x;
  int wsel = bid & 3;
  int cg = (bid >> 2) & 7;
  int b = bid >> 5;
  int w0 = wsel * 32;
  float g = gamma[0];
  const int PL = HW * HW;  // 16384

  // A: per-pixel alphas for the 32(w) x 128(h) stripe.
  #pragma unroll
  for (int it = 0; it < 16; ++it) {
    int p = t + 256 * it;
    int w = p & 31, h = p >> 5;
    float mw = mW[b * PL + h * HW + w0 + w];
    float sw = sW[b * PL + h * HW + w0 + w];
    float mh = mH[b * PL + (w0 + w) * HW + h];
    float sh = sH[b * PL + (w0 + w) * HW + h];
    float mm = fmaxf(mh, mw);
    float eh = __expf(mh - mm), ew = __expf(mw - mm);
    float inv = 1.f / (sh * eh + sw * ew);
    aH_l[w * 132 + h] = eh * inv;
    aW_l[h * 33 + w] = ew * inv;
  }
  __syncthreads();

  for (int ci = 0; ci < 8; ++ci) {
    int c = cg * 8 + ci;
    size_t cbase = (size_t)(b * CC + c) * PL;
    // B1: oHT rows (transposed layout, contiguous h) -> tile[w][h] scaled by aH
    #pragma unroll
    for (int i = 0; i < 2; ++i) {
      int p = t + 256 * i;
      int w = p >> 4, hg = p & 15;
      uv4 ov = *(const uv4*)(oHT + cbase + (size_t)(w0 + w) * HW + hg * 8);
      float* trow = &tile[w * 132 + hg * 8];
      const float* arow = &aH_l[w * 132 + hg * 8];
      #pragma unroll
      for (int j = 0; j < 8; ++j) {
        ushort u = (ushort)((ov[j >> 1] >> ((j & 1) * 16)) & 0xffff);
        trow[j] = h2f(u) * arow[j];
      }
    }
    __syncthreads();
    // B2: natural rows: oW (uint2=4 f16), x/out (float4)
    #pragma unroll
    for (int it = 0; it < 4; ++it) {
      int p = t + 256 * it;
      int w4 = p & 7, h = p >> 3;
      size_t base = cbase + (size_t)h * HW + w0 + 4 * w4;
      uint2 ow2 = *(const uint2*)(oW + base);
      float4 xv = *(const float4*)(x + base);
      const float* aw = &aW_l[h * 33 + 4 * w4];
      float r[4];
      #pragma unroll
      for (int j = 0; j < 4; ++j) {
        ushort u = (ushort)(((j < 2 ? ow2.x : ow2.y) >> ((j & 1) * 16)) & 0xffff);
        float th = tile[(4 * w4 + j) * 132 + h];
        r[j] = g * (th + h2f(u) * aw[j]);
      }
      float4 res = { r[0] + xv.x, r[1] + xv.y, r[2] + xv.z, r[3] + xv.w };
      *(float4*)(out + base) = res;
    }
    __syncthreads();
  }
}

extern "C" void kernel_launch(void* const* d_in, const int* in_sizes, int n_in,
                              void* d_out, int out_size, void* d_ws, size_t ws_size,
                              hipStream_t stream)
{
  const float* x     = (const float*)d_in[0];
  const float* Wq    = (const float*)d_in[1];
  const float* bq    = (const float*)d_in[2];
  const float* Wk    = (const float*)d_in[3];
  const float* bk    = (const float*)d_in[4];
  const float* Wv    = (const float*)d_in[5];
  const float* bv    = (const float*)d_in[6];
  const float* gamma = (const float*)d_in[7];
  float* out = (float*)d_out;

  char* w = (char*)d_ws;
  size_t np = (size_t)NB * HW * HW;
  ushort* q   = (ushort*)w;  w += np * C8V * 2;
  ushort* k   = (ushort*)w;  w += np * C8V * 2;
  ushort* qT  = (ushort*)w;  w += np * C8V * 2;
  ushort* kT  = (ushort*)w;  w += np * C8V * 2;
  ushort* v   = (ushort*)w;  w += np * CC * 2;
  ushort* vT  = (ushort*)w;  w += np * CC * 2;
  ushort* oW  = (ushort*)w;  w += np * CC * 2;
  ushort* oHT = (ushort*)w;  w += np * CC * 2;
  float* mW = (float*)w;  w += np * 4;
  float* sW = (float*)w;  w += np * 4;
  float* mH = (float*)w;  w += np * 4;
  float* sH = (float*)w;  w += np * 4;
  if ((size_t)(w - (char*)d_ws) > ws_size) return;

  k_proj<<<NB * HW, 256, 0, stream>>>(x, Wq, bq, Wk, bk, Wv, bv, q, k, v);
  k_transpose_all<<<256 + NB * CC, 256, 0, stream>>>(q, qT, k, kT, v, vT);
  k_attn<false><<<NB * HW, 256, 0, stream>>>(q,  k,  v,  oW,  mW, sW);
  k_attn<true ><<<NB * HW, 256, 0, stream>>>(qT, kT, vT, oHT, mH, sH);
  k_merge<<<NB * 32, 256, 0, stream>>>(oHT, oW, mH, sH, mW, sW, x, gamma, out);
}

// Round 4
// 123.865 us; speedup vs baseline: 2.0909x; 1.0374x over previous
//
#include <hip/hip_runtime.h>

#define HW 128      // H == W
#define CC 64       // C
#define C8V 8       // C/8
#define NB 16       // B

typedef _Float16 h1;
typedef _Float16 h2 __attribute__((ext_vector_type(2)));
typedef _Float16 half8 __attribute__((ext_vector_type(8)));
typedef float float16v __attribute__((ext_vector_type(16)));
typedef uint uv4 __attribute__((ext_vector_type(4)));

__device__ __forceinline__ uint packh2(float a, float b) {
#if __has_builtin(__builtin_amdgcn_cvt_pkrtz)
  return __builtin_bit_cast(uint, __builtin_amdgcn_cvt_pkrtz(a, b));
#else
  h2 v; v[0] = (h1)a; v[1] = (h1)b; return __builtin_bit_cast(uint, v);
#endif
}
__device__ __forceinline__ ushort f2h(float a) { h1 v = (h1)a; return __builtin_bit_cast(ushort, v); }
__device__ __forceinline__ float  h2f(ushort a) { return (float)__builtin_bit_cast(h1, a); }

__device__ __forceinline__ float16v mfma16(uv4 a, uv4 b, float16v c) {
  return __builtin_amdgcn_mfma_f32_32x32x16_f16(
      __builtin_bit_cast(half8, a), __builtin_bit_cast(half8, b), c, 0, 0, 0);
}

// ---------------------------------------------------------------------------
// K1: projection GEMM via MFMA. One block per (b, h) row, 4 waves.
// ---------------------------------------------------------------------------
__global__ __launch_bounds__(256) void k_proj(
    const float* __restrict__ x,
    const float* __restrict__ Wq, const float* __restrict__ bq,
    const float* __restrict__ Wk, const float* __restrict__ bk,
    const float* __restrict__ Wv, const float* __restrict__ bv,
    ushort* __restrict__ q, ushort* __restrict__ k, ushort* __restrict__ v)
{
  alignas(16) __shared__ ushort smem[16128];   // x_l[128][72] | W_l[96][72]; o_l[80][128] aliases
  __shared__ float bias_l[96];
  ushort* x_l = smem;                 // [w][c], row stride 72
  ushort* W_l = smem + 128 * 72;      // [o][c], row stride 72

  int t = threadIdx.x;
  int lane = t & 63, wv = t >> 6;
  int b = blockIdx.x >> 7, r = blockIdx.x & 127;

  #pragma unroll
  for (int i = 0; i < 20; ++i) {
    int idx = t + 256 * i; int o_ = idx >> 6, c = idx & 63;
    float wval = (o_ < 8) ? Wq[o_ * 64 + c] : (o_ < 16) ? Wk[(o_ - 8) * 64 + c] : Wv[(o_ - 16) * 64 + c];
    W_l[o_ * 72 + c] = f2h(wval);
  }
  if (t < 96) bias_l[t] = (t < 8) ? bq[t] : (t < 16) ? bk[t - 8] : (t < 80) ? bv[t - 16] : 0.f;

  const float* xrow = x + (size_t)(b * CC) * (HW * HW) + (size_t)r * HW;
  #pragma unroll
  for (int i = 0; i < 8; ++i) {
    int idx = t + 256 * i; int c = idx >> 5, w4 = idx & 31;
    float4 xv = *(const float4*)(xrow + (size_t)c * (HW * HW) + w4 * 4);
    x_l[(w4 * 4 + 0) * 72 + c] = f2h(xv.x);
    x_l[(w4 * 4 + 1) * 72 + c] = f2h(xv.y);
    x_l[(w4 * 4 + 2) * 72 + c] = f2h(xv.z);
    x_l[(w4 * 4 + 3) * 72 + c] = f2h(xv.w);
  }
  __syncthreads();

  int w = 32 * wv + (lane & 31);
  float16v acc0 = {}, acc1 = {}, acc2 = {};
  #pragma unroll
  for (int ks = 0; ks < 4; ++ks) {
    int c0 = 8 * (lane >> 5) + 16 * ks;
    uv4 Bx = *(const uv4*)&x_l[w * 72 + c0];
    uv4 a0 = *(const uv4*)&W_l[((lane & 31) + 0) * 72 + c0];
    uv4 a1 = *(const uv4*)&W_l[((lane & 31) + 32) * 72 + c0];
    uv4 a2 = *(const uv4*)&W_l[((lane & 31) + 64) * 72 + c0];
    acc0 = mfma16(a0, Bx, acc0);
    acc1 = mfma16(a1, Bx, acc1);
    acc2 = mfma16(a2, Bx, acc2);
  }
  __syncthreads();

  ushort* o_l = smem;
  int hi = lane >> 5;
  #pragma unroll
  for (int reg = 0; reg < 16; ++reg) {
    int orow = (reg & 3) + 8 * (reg >> 2) + 4 * hi;
    o_l[(orow +  0) * 128 + w] = f2h(acc0[reg] + bias_l[orow]);
    o_l[(orow + 32) * 128 + w] = f2h(acc1[reg] + bias_l[orow + 32]);
    if (orow + 64 < 80)
      o_l[(orow + 64) * 128 + w] = f2h(acc2[reg] + bias_l[orow + 64]);
  }
  __syncthreads();

  ushort* qb = q + (size_t)(b * C8V) * (HW * HW) + (size_t)r * HW;
  ushort* kb = k + (size_t)(b * C8V) * (HW * HW) + (size_t)r * HW;
  ushort* vb = v + (size_t)(b * CC)  * (HW * HW) + (size_t)r * HW;
  #pragma unroll
  for (int i = 0; i < 5; ++i) {
    int idx = t + 256 * i; int o_ = idx >> 4, w8 = idx & 15;
    uv4 val = *(const uv4*)&o_l[o_ * 128 + w8 * 8];
    ushort* dst = (o_ < 8) ? qb + (size_t)o_ * (HW * HW)
                : (o_ < 16) ? kb + (size_t)(o_ - 8) * (HW * HW)
                            : vb + (size_t)(o_ - 16) * (HW * HW);
    *(uv4*)(dst + w8 * 8) = val;
  }
}

// ---------------------------------------------------------------------------
// K2: all three plane transposes in ONE launch (q->qT, k->kT, v->vT).
// ---------------------------------------------------------------------------
__global__ __launch_bounds__(256) void k_transpose_all(
    const ushort* __restrict__ q, ushort* __restrict__ qT,
    const ushort* __restrict__ k, ushort* __restrict__ kT,
    const ushort* __restrict__ v, ushort* __restrict__ vT)
{
  __shared__ ushort tl[128 * 130];
  int t = threadIdx.x;
  int p = blockIdx.x;
  const ushort* in; ushort* out;
  if (p < 128)      { size_t base = (size_t)p * (HW * HW);         in = q + base; out = qT + base; }
  else if (p < 256) { size_t base = (size_t)(p - 128) * (HW * HW); in = k + base; out = kT + base; }
  else              { size_t base = (size_t)(p - 256) * (HW * HW); in = v + base; out = vT + base; }
  const uint* ip = (const uint*)in;
  uint* op = (uint*)out;
  int c2 = t & 63;
  int r0 = t >> 6;
  for (int it = 0; it < 32; ++it) {
    int r = it * 4 + r0;
    uint val = ip[r * 64 + c2];
    *(uint*)&tl[r * 130 + c2 * 2] = val;
  }
  __syncthreads();
  for (int it = 0; it < 32; ++it) {
    int wcol = it * 4 + r0;
    int hh = c2 * 2;
    uint lo = tl[hh * 130 + wcol];
    uint hi = tl[(hh + 1) * 130 + wcol];
    op[wcol * 64 + c2] = lo | (hi << 16);
  }
}

// ---------------------------------------------------------------------------
// K3: MFMA row attention, BOTH passes in one launch. blocks [0,2048) = W-pass
// (no mask, natural layout), [2048,4096) = H-pass (diag mask, transposed).
// ---------------------------------------------------------------------------
__global__ __launch_bounds__(256) void k_attn_both(
    const ushort* __restrict__ q,  const ushort* __restrict__ kkn, const ushort* __restrict__ vn,
    const ushort* __restrict__ qT, const ushort* __restrict__ kkT, const ushort* __restrict__ vT,
    ushort* __restrict__ oW_, float* __restrict__ mW_, float* __restrict__ sW_,
    ushort* __restrict__ oH_, float* __restrict__ mH_, float* __restrict__ sH_)
{
  alignas(16) __shared__ ushort Q_l[128][16];
  alignas(16) __shared__ ushort K_l[128][16];
  alignas(16) __shared__ uint   V_l[64 * 64];

  int t = threadIdx.x;
  int lane = t & 63, wv = t >> 6;
  int hi = lane >> 5;
  int bid = blockIdx.x & 2047;
  bool maskf = blockIdx.x >= 2048;
  const ushort* qp = maskf ? qT : q;
  const ushort* kp = maskf ? kkT : kkn;
  const ushort* vp = maskf ? vT : vn;
  ushort* op = maskf ? oH_ : oW_;
  float* mo = maskf ? mH_ : mW_;
  float* so = maskf ? sH_ : sW_;

  int b = bid >> 7, r = bid & 127;
  size_t plane32 = (size_t)(HW * HW) / 2;

  if (t < 128) {
    *(uv4*)&Q_l[t][8] = (uv4){0, 0, 0, 0};
    *(uv4*)&K_l[t][8] = (uv4){0, 0, 0, 0};
  }
  const uint* qrow = (const uint*)qp + (size_t)(b * C8V) * plane32 + (size_t)r * 64;
  const uint* krow = (const uint*)kp + (size_t)(b * C8V) * plane32 + (size_t)r * 64;
  #pragma unroll
  for (int i = 0; i < 2; ++i) {
    int idx = t + 256 * i; int c = idx >> 6, w2 = idx & 63;
    uint qv = qrow[(size_t)c * plane32 + w2];
    Q_l[2 * w2][c] = (ushort)(qv & 0xffff); Q_l[2 * w2 + 1][c] = (ushort)(qv >> 16);
    uint kv = krow[(size_t)c * plane32 + w2];
    K_l[2 * w2][c] = (ushort)(kv & 0xffff); K_l[2 * w2 + 1][c] = (ushort)(kv >> 16);
  }
  const uint* vrow = (const uint*)vp + (size_t)(b * CC) * plane32 + (size_t)r * 64;
  #pragma unroll
  for (int i = 0; i < 16; ++i) {
    int idx = t + 256 * i; int c = idx >> 6, j2 = idx & 63;
    uint val = vrow[(size_t)c * plane32 + j2];
    uint byteoff = c * 256 + ((4 * j2) ^ ((c & 15) << 4));
    V_l[byteoff >> 2] = val;
  }
  __syncthreads();

  uv4 Bq = *(const uv4*)&Q_l[(lane & 31) + 32 * wv][hi * 8];
  float16v e[4];
  #pragma unroll
  for (int mt = 0; mt < 4; ++mt) {
    uv4 ka = *(const uv4*)&K_l[(lane & 31) + 32 * mt][hi * 8];
    float16v z = {};
    e[mt] = mfma16(ka, Bq, z);
  }

  int qg = 32 * wv + (lane & 31);
  float m = -INFINITY;
  #pragma unroll
  for (int mt = 0; mt < 4; ++mt) {
    #pragma unroll
    for (int reg = 0; reg < 16; ++reg) {
      float ev = e[mt][reg];
      if (maskf) {
        int key = 32 * mt + ((reg & 3) + 8 * (reg >> 2) + 4 * hi);
        ev = (key == qg) ? -INFINITY : ev;
        e[mt][reg] = ev;
      }
      m = fmaxf(m, ev);
    }
  }
  m = fmaxf(m, __shfl_xor(m, 32));
  float s = 0.f;
  #pragma unroll
  for (int mt = 0; mt < 4; ++mt) {
    #pragma unroll
    for (int reg = 0; reg < 16; ++reg) {
      float p = __expf(e[mt][reg] - m);
      e[mt][reg] = p;
      s += p;
    }
  }
  s += __shfl_xor(s, 32);
  if (lane < 32) {
    mo[(size_t)bid * HW + qg] = m;
    so[(size_t)bid * HW + qg] = s;
  }

  float16v acc0 = {}, acc1 = {};
  #pragma unroll
  for (int s8 = 0; s8 < 8; ++s8) {
    int mt = s8 >> 1, hf = s8 & 1;
    float p0 = e[mt][8 * hf + 0], p1 = e[mt][8 * hf + 1];
    float p2 = e[mt][8 * hf + 2], p3 = e[mt][8 * hf + 3];
    float p4 = e[mt][8 * hf + 4], p5 = e[mt][8 * hf + 5];
    float p6 = e[mt][8 * hf + 6], p7 = e[mt][8 * hf + 7];
    uint X = packh2(p0, p1), Y = packh2(p2, p3), Z = packh2(p4, p5), Wp = packh2(p6, p7);
    uint Xs = __shfl_xor(X, 32), Ys = __shfl_xor(Y, 32);
    uint Zs = __shfl_xor(Z, 32), Ws = __shfl_xor(Wp, 32);
    uv4 Bp;
    Bp[0] = (hi == 0) ? X  : Zs;
    Bp[1] = (hi == 0) ? Y  : Ws;
    Bp[2] = (hi == 0) ? Xs : Z;
    Bp[3] = (hi == 0) ? Ys : Wp;
    #pragma unroll
    for (int ct = 0; ct < 2; ++ct) {
      int c = (lane & 31) + 32 * ct;
      uint byteoff = c * 256 + ((16 * (hi + 2 * s8)) ^ ((c & 15) << 4));
      uv4 va = *(const uv4*)((const char*)V_l + byteoff);
      if (ct == 0) acc0 = mfma16(va, Bp, acc0);
      else         acc1 = mfma16(va, Bp, acc1);
    }
  }

  __syncthreads();
  ushort* o_l = (ushort*)V_l;
  int w = 32 * wv + (lane & 31);
  #pragma unroll
  for (int reg = 0; reg < 16; ++reg) {
    int c = (reg & 3) + 8 * (reg >> 2) + 4 * hi;
    o_l[(c +  0) * 128 + w] = f2h(acc0[reg]);
    o_l[(c + 32) * 128 + w] = f2h(acc1[reg]);
  }
  __syncthreads();
  ushort* ob = op + (size_t)(b * CC) * (HW * HW) + (size_t)r * HW;
  #pragma unroll
  for (int i = 0; i < 4; ++i) {
    int idx = t + 256 * i; int c = idx >> 4, w8 = idx & 15;
    *(uv4*)(ob + (size_t)c * (HW * HW) + w8 * 8) = *(const uv4*)&o_l[c * 128 + w8 * 8];
  }
}

// ---------------------------------------------------------------------------
// K4 (v3): merge. Block = (b, 4-ch group, 32-w stripe, full 128 h). Grid 1024.
// 3 barriers/block. All global accesses vectorized. oHT pre-scaled by alphaH
// during LDS staging; consume reads 2-h-packed uints (2-way bank = free).
// ---------------------------------------------------------------------------
__global__ __launch_bounds__(256) void k_merge(
    const ushort* __restrict__ oHT, const ushort* __restrict__ oW,
    const float* __restrict__ mH, const float* __restrict__ sH,
    const float* __restrict__ mW, const float* __restrict__ sW,
    const float* __restrict__ x, const float* __restrict__ gamma,
    float* __restrict__ out)
{
  __shared__ float aH_l[32 * 129];                    // [w][h]
  __shared__ float aW_l[128 * 36];                    // [h][w], float4-aligned rows
  alignas(16) __shared__ ushort otile[4 * 32 * 132];  // [ch][w][h] prescaled; aliased as tmp
  float* tmpM = (float*)otile;                        // [w][h] stride 129
  float* tmpS = tmpM + 32 * 129;

  int t = threadIdx.x;
  int bid = blockIdx.x;
  int wsel = bid & 3, cg = (bid >> 2) & 15, b = bid >> 6;
  int w0 = wsel * 32;
  float g = gamma[0];
  const int PL = HW * HW;
  const float* mHb = mH + (size_t)b * PL;
  const float* sHb = sH + (size_t)b * PL;
  const float* mWb = mW + (size_t)b * PL;
  const float* sWb = sW + (size_t)b * PL;

  // A1: stage H-pass stats (transposed layout, coalesced along h)
  #pragma unroll
  for (int i = 0; i < 16; ++i) {
    int p = t + 256 * i; int h = p & 127, w = p >> 7;
    tmpM[w * 129 + h] = mHb[(w0 + w) * HW + h];
    tmpS[w * 129 + h] = sHb[(w0 + w) * HW + h];
  }
  __syncthreads();
  // A2: alphas
  #pragma unroll
  for (int i = 0; i < 16; ++i) {
    int p = t + 256 * i; int w = p & 31, h = p >> 5;
    float mw = mWb[h * HW + w0 + w], sw = sWb[h * HW + w0 + w];
    float mh = tmpM[w * 129 + h],    sh = tmpS[w * 129 + h];
    float mm = fmaxf(mh, mw);
    float eh = __expf(mh - mm), ew = __expf(mw - mm);
    float inv = 1.f / (sh * eh + sw * ew);
    aH_l[w * 129 + h] = eh * inv;
    aW_l[h * 36 + w]  = ew * inv;
  }
  __syncthreads();

  // B-stage: oHT tiles, prescaled by alphaH, f16 -> otile (overwrites tmp)
  #pragma unroll
  for (int i = 0; i < 8; ++i) {
    int p = t + 256 * i;             // 0..2047
    int ch = p >> 9, rest = p & 511;
    int w = rest >> 4, hg = rest & 15;
    size_t cbase = (size_t)(b * CC + cg * 4 + ch) * PL;
    uv4 ov = *(const uv4*)(oHT + cbase + (size_t)(w0 + w) * HW + hg * 8);
    const float* ah = &aH_l[w * 129 + hg * 8];
    uint res[4];
    #pragma unroll
    for (int jj = 0; jj < 4; ++jj) {
      float lo = h2f((ushort)(ov[jj] & 0xffff)) * ah[2 * jj];
      float hi = h2f((ushort)(ov[jj] >> 16))    * ah[2 * jj + 1];
      res[jj] = packh2(lo, hi);
    }
    ushort* dst = &otile[(ch * 32 + w) * 132 + hg * 8];
    *(uint2*)dst       = make_uint2(res[0], res[1]);
    *(uint2*)(dst + 4) = make_uint2(res[2], res[3]);
  }
  __syncthreads();

  // B-consume: stream natural-layout rows
  #pragma unroll
  for (int ch = 0; ch < 4; ++ch) {
    size_t cbase = (size_t)(b * CC + cg * 4 + ch) * PL;
    const ushort* otc = &otile[ch * 32 * 132];
    #pragma unroll
    for (int i = 0; i < 2; ++i) {
      int p = t + 256 * i;            // 0..511
      int w4 = p & 7, h2 = p >> 3;    // h2 0..63
      float th0[4], th1[4];
      #pragma unroll
      for (int j = 0; j < 4; ++j) {
        uint pk = *(const uint*)&otc[(4 * w4 + j) * 132 + 2 * h2];
        th0[j] = h2f((ushort)(pk & 0xffff));
        th1[j] = h2f((ushort)(pk >> 16));
      }
      #pragma unroll
      for (int rr = 0; rr < 2; ++rr) {
        int hh = 2 * h2 + rr;
        const float* th = rr ? th1 : th0;
        size_t base = cbase + (size_t)hh * HW + w0 + 4 * w4;
        float4 aw = *(const float4*)&aW_l[hh * 36 + 4 * w4];
        uint2 ow2 = *(const uint2*)(oW + base);
        float4 xv = *(const float4*)(x + base);
        float4 res;
        res.x = g * (th[0] + h2f((ushort)(ow2.x & 0xffff)) * aw.x) + xv.x;
        res.y = g * (th[1] + h2f((ushort)(ow2.x >> 16))    * aw.y) + xv.y;
        res.z = g * (th[2] + h2f((ushort)(ow2.y & 0xffff)) * aw.z) + xv.z;
        res.w = g * (th[3] + h2f((ushort)(ow2.y >> 16))    * aw.w) + xv.w;
        *(float4*)(out + base) = res;
      }
    }
  }
}

extern "C" void kernel_launch(void* const* d_in, const int* in_sizes, int n_in,
                              void* d_out, int out_size, void* d_ws, size_t ws_size,
                              hipStream_t stream)
{
  const float* x     = (const float*)d_in[0];
  const float* Wq    = (const float*)d_in[1];
  const float* bq    = (const float*)d_in[2];
  const float* Wk    = (const float*)d_in[3];
  const float* bk    = (const float*)d_in[4];
  const float* Wv    = (const float*)d_in[5];
  const float* bv    = (const float*)d_in[6];
  const float* gamma = (const float*)d_in[7];
  float* out = (float*)d_out;

  char* w = (char*)d_ws;
  size_t np = (size_t)NB * HW * HW;
  ushort* q   = (ushort*)w;  w += np * C8V * 2;
  ushort* k   = (ushort*)w;  w += np * C8V * 2;
  ushort* qT  = (ushort*)w;  w += np * C8V * 2;
  ushort* kT  = (ushort*)w;  w += np * C8V * 2;
  ushort* v   = (ushort*)w;  w += np * CC * 2;
  ushort* vT  = (ushort*)w;  w += np * CC * 2;
  ushort* oW  = (ushort*)w;  w += np * CC * 2;
  ushort* oHT = (ushort*)w;  w += np * CC * 2;
  float* mW = (float*)w;  w += np * 4;
  float* sW = (float*)w;  w += np * 4;
  float* mH = (float*)w;  w += np * 4;
  float* sH = (float*)w;  w += np * 4;
  if ((size_t)(w - (char*)d_ws) > ws_size) return;

  k_proj<<<NB * HW, 256, 0, stream>>>(x, Wq, bq, Wk, bk, Wv, bv, q, k, v);
  k_transpose_all<<<256 + NB * CC, 256, 0, stream>>>(q, qT, k, kT, v, vT);
  k_attn_both<<<2 * NB * HW, 256, 0, stream>>>(q, k, v, qT, kT, vT,
                                               oW, mW, sW, oHT, mH, sH);
  k_merge<<<NB * 16 * 4, 256, 0, stream>>>(oHT, oW, mH, sH, mW, sW, x, gamma, out);
}